// Round 12
// baseline (238.080 us; speedup 1.0000x reference)
//
#include <hip/hip_runtime.h>

#define BB 4
#define LL 1024
#define EE 1024
#define HH 16
#define HD 64
#define NBUCKET 33
#define SCALE 0.125f
#define SC2 (0.125f * 1.44269504088896f)

typedef unsigned short u16;
using f32x4 = __attribute__((ext_vector_type(4))) float;
using s16x8 = __attribute__((ext_vector_type(8))) short;

__device__ __forceinline__ u16 f2bf(float f) {
  union { float f; unsigned u; } x; x.f = f;
  unsigned r = (x.u + 0x7fffu + ((x.u >> 16) & 1u)) >> 16;
  return (u16)r;
}

__device__ __forceinline__ void gld_lds16(const void* g, void* s) {
  __builtin_amdgcn_global_load_lds((const __attribute__((address_space(1))) void*)g,
                                   (__attribute__((address_space(3))) void*)s, 16, 0, 0);
}

// ---------------- weights + rel_k fp32->bf16 (inputs converted in proj_gemm) ----
__global__ __launch_bounds__(256) void cvt_w(
    const float* __restrict__ wq, const float* __restrict__ wk, const float* __restrict__ wv,
    const float* __restrict__ wo, const float* __restrict__ rk,
    u16* __restrict__ owq, u16* __restrict__ owk, u16* __restrict__ owv,
    u16* __restrict__ owo, u16* __restrict__ ork) {
  const int bid = blockIdx.x;
  const int tid = threadIdx.x;
  if (bid < 4096) {
    const int z = bid >> 10;
    const int i = (bid & 1023) * 256 + tid;
    const float* in = z == 0 ? wq : (z == 1 ? wk : (z == 2 ? wv : wo));
    u16* out = z == 0 ? owq : (z == 1 ? owk : (z == 2 ? owv : owo));
    float4 f = ((const float4*)in)[i];
    ushort4 o;
    o.x = f2bf(f.x); o.y = f2bf(f.y); o.z = f2bf(f.z); o.w = f2bf(f.w);
    ((ushort4*)out)[i] = o;
  } else {
    const int i = (bid - 4096) * 256 + tid;  // 12*256 = 3072 = 48*64 exact
    ork[i] = (i < 33 * 64) ? f2bf(rk[i]) : (u16)0;
  }
}

// ---- 128x128x64 dbuf GEMM, A fp32 (T14 reg-staged cvt), B^T bf16 via DMA ----
// Round-12: removes the q/k/v pre-convert pass (72 MB HBM). Per iter: issue
// next A-tile f32 loads to REGISTERS + next B-tile DMA at iter TOP; compute
// MFMAs on cur; then cvt_pk + swizzled ds_write of A (the compiler's vmcnt
// wait for the A loads lands here — a full compute phase after issue = T14);
// one {vmcnt(0); lgkmcnt(0); barrier} at iter END (drains B DMA + ds_writes).
// Next-A writes target buffer last read in iter kt-1 (fenced). Swizzle and
// XCD remap identical to the round-8-proven path.
// MODE 0: bf16 (B,H,L,HD). MODE 2: bf16 (B,H,HD,L).
template <int MODE>
__device__ __forceinline__ void gemm128_f32a_dbuf(u16* __restrict__ sm,  // 4 x 8192 u16
                                                  const float* __restrict__ A,
                                                  const u16* __restrict__ Bw,
                                                  const float* __restrict__ bias,
                                                  u16* __restrict__ obf,
                                                  int K, int m0, int n0) {
  const int tid = threadIdx.x;
  const int wave = tid >> 6, lane = tid & 63;
  const int row16 = lane & 15, quad = lane >> 4;
  const int wr = (wave >> 1) * 64, wc = (wave & 1) * 64;
  const int srow = lane >> 3, scol = (lane & 7) * 8;
  const int rsw = (row16 & 7) * 8;  // frag-read XOR (u16 units)

  f32x4 acc[4][4] = {};

  auto stageB = [&](int k0, u16* bs) {
#pragma unroll
    for (int t = 0; t < 4; ++t) {
      const int chunk = wave * 4 + t;
      const int r = chunk * 8 + srow;
      const int cs = scol ^ ((r & 7) * 8);
      gld_lds16(Bw + (size_t)(n0 + r) * K + k0 + cs, bs + chunk * 512);
    }
  };
  auto loadA = [&](int k0, float4* fr) {
#pragma unroll
    for (int p = 0; p < 4; ++p) {
      const int pc = p * 256 + tid;
      const int ar = pc >> 3, ac0 = (pc & 7) * 8;
      const float4* src = (const float4*)(A + (size_t)(m0 + ar) * K + k0 + ac0);
      fr[2 * p] = src[0];
      fr[2 * p + 1] = src[1];
    }
  };
  auto writeA = [&](const float4* fr, u16* as) {
#pragma unroll
    for (int p = 0; p < 4; ++p) {
      const int pc = p * 256 + tid;
      const int ar = pc >> 3, ac0 = (pc & 7) * 8;
      const float4 f0 = fr[2 * p], f1 = fr[2 * p + 1];
      unsigned w0, w1, w2, w3;
      asm("v_cvt_pk_bf16_f32 %0, %1, %2" : "=v"(w0) : "v"(f0.x), "v"(f0.y));
      asm("v_cvt_pk_bf16_f32 %0, %1, %2" : "=v"(w1) : "v"(f0.z), "v"(f0.w));
      asm("v_cvt_pk_bf16_f32 %0, %1, %2" : "=v"(w2) : "v"(f1.x), "v"(f1.y));
      asm("v_cvt_pk_bf16_f32 %0, %1, %2" : "=v"(w3) : "v"(f1.z), "v"(f1.w));
      union { unsigned u[4]; s16x8 v; } w;
      w.u[0] = w0; w.u[1] = w1; w.u[2] = w2; w.u[3] = w3;
      *(s16x8*)&as[ar * 64 + (ac0 ^ ((ar & 7) * 8))] = w.v;
    }
  };

  // prologue: stage tile 0 (A reg->cvt->LDS, B DMA), drain, barrier
  float4 fr[8];
  loadA(0, fr);
  stageB(0, sm + 8192);
  writeA(fr, sm);
  asm volatile("s_waitcnt vmcnt(0) lgkmcnt(0)" ::: "memory");
  __builtin_amdgcn_s_barrier();
  __builtin_amdgcn_sched_barrier(0);

  const int NK = K >> 6;
  for (int kt = 0; kt < NK; ++kt) {
    u16* as = sm + (kt & 1) * 16384;
    u16* bs = as + 8192;
    u16* an = sm + ((kt & 1) ^ 1) * 16384;
    if (kt + 1 < NK) {
      loadA((kt + 1) << 6, fr);          // T14 issue: f32 A -> regs
      stageB((kt + 1) << 6, an + 8192);  // B DMA -> alt buffer
    }
#pragma unroll
    for (int ks = 0; ks < 2; ++ks) {
      const int cfs = (ks * 32 + quad * 8) ^ rsw;
      s16x8 af[4], bf[4];
#pragma unroll
      for (int mi = 0; mi < 4; ++mi)
        af[mi] = *(const s16x8*)&as[(wr + mi * 16 + row16) * 64 + cfs];
#pragma unroll
      for (int ni = 0; ni < 4; ++ni)
        bf[ni] = *(const s16x8*)&bs[(wc + ni * 16 + row16) * 64 + cfs];
#pragma unroll
      for (int mi = 0; mi < 4; ++mi)
#pragma unroll
        for (int ni = 0; ni < 4; ++ni)
          acc[mi][ni] = __builtin_amdgcn_mfma_f32_16x16x32_bf16(af[mi], bf[ni], acc[mi][ni], 0, 0, 0);
    }
    if (kt + 1 < NK) writeA(fr, an);  // T14 write: vmcnt waited here, post-compute
    asm volatile("s_waitcnt vmcnt(0) lgkmcnt(0)" ::: "memory");
    __builtin_amdgcn_s_barrier();
    __builtin_amdgcn_sched_barrier(0);
  }

#pragma unroll
  for (int mi = 0; mi < 4; ++mi)
#pragma unroll
    for (int ni = 0; ni < 4; ++ni) {
      const int n = n0 + wc + ni * 16 + row16;
      const float bn = bias[n];
      if (MODE == 2) {
        const int mr0 = m0 + wr + mi * 16 + quad * 4;
        const int b = mr0 >> 10, l = mr0 & 1023;
        const int h = n >> 6, hd = n & 63;
        ushort4 o;
        o.x = f2bf(acc[mi][ni][0] + bn);
        o.y = f2bf(acc[mi][ni][1] + bn);
        o.z = f2bf(acc[mi][ni][2] + bn);
        o.w = f2bf(acc[mi][ni][3] + bn);
        *(ushort4*)&obf[((size_t)((b * HH + h) * HD + hd)) * LL + l] = o;
      } else {
#pragma unroll
        for (int r = 0; r < 4; ++r) {
          const int m = m0 + wr + mi * 16 + quad * 4 + r;
          const float v = acc[mi][ni][r] + bn;
          const int b = m >> 10, l = m & 1023, h = n >> 6, hd = n & 63;
          obf[((size_t)((b * HH + h) * LL + l)) * HD + hd] = f2bf(v);
        }
      }
    }
}

__global__ __launch_bounds__(256) void proj_gemm(
    const float* __restrict__ xq, const float* __restrict__ xk, const float* __restrict__ xv,
    const u16* __restrict__ wqb, const u16* __restrict__ wkb, const u16* __restrict__ wvb,
    const float* __restrict__ bq, const float* __restrict__ bk, const float* __restrict__ bv,
    u16* __restrict__ oq, u16* __restrict__ ok, u16* __restrict__ ovt) {
  __shared__ u16 sm[4 * 8192];  // dbuf: {a0,b0,a1,b1}
  const int work = (blockIdx.x & 7) * 96 + (blockIdx.x >> 3);
  const int z = work >> 8;
  const int m0 = ((work & 255) >> 3) * 128;
  const int n0 = (work & 7) * 128;
  if (z == 0)
    gemm128_f32a_dbuf<0>(sm, xq, wqb, bq, oq, EE, m0, n0);
  else if (z == 1)
    gemm128_f32a_dbuf<0>(sm, xk, wkb, bk, ok, EE, m0, n0);
  else  // V: store directly transposed (B,H,HD,L)
    gemm128_f32a_dbuf<2>(sm, xv, wvb, bv, ovt, EE, m0, n0);
}

// ---------------- out projection: 64x128x64 dbuf GEMM (round-10-proven) --------
__global__ __launch_bounds__(256) void out_gemm(const u16* __restrict__ A,
                                                const u16* __restrict__ Bw,
                                                const float* __restrict__ bo,
                                                float* __restrict__ out) {
  __shared__ u16 sm[2 * 12288];  // per buf: A 4096 u16 (64x64) | B 8192 u16 (128x64)
  const int work = (blockIdx.x & 7) * 64 + (blockIdx.x >> 3);
  const int m0 = (work >> 3) * 64;
  const int n0 = (work & 7) * 128;
  const int K = EE, N = EE;

  const int tid = threadIdx.x;
  const int wave = tid >> 6, lane = tid & 63;
  const int row16 = lane & 15, quad = lane >> 4;
  const int wm = (wave >> 1) * 32, wn = (wave & 1) * 64;
  const int srow = lane >> 3, scol = (lane & 7) * 8;
  const int rsw = (row16 & 7) * 8;

  f32x4 acc[2][4] = {};

  auto stage = [&](int k0, u16* as, u16* bs) {
#pragma unroll
    for (int t = 0; t < 2; ++t) {
      const int chunk = wave * 2 + t;
      const int r = chunk * 8 + srow;
      const int cs = scol ^ ((r & 7) * 8);
      gld_lds16(A + (size_t)(m0 + r) * K + k0 + cs, as + chunk * 512);
    }
#pragma unroll
    for (int t = 0; t < 4; ++t) {
      const int chunk = wave * 4 + t;
      const int r = chunk * 8 + srow;
      const int cs = scol ^ ((r & 7) * 8);
      gld_lds16(Bw + (size_t)(n0 + r) * K + k0 + cs, bs + chunk * 512);
    }
  };

  stage(0, sm, sm + 4096);
  asm volatile("s_waitcnt vmcnt(0)" ::: "memory");
  __builtin_amdgcn_s_barrier();
  __builtin_amdgcn_sched_barrier(0);

  for (int kt = 0; kt < 16; ++kt) {
    u16* as = sm + (kt & 1) * 12288;
    u16* bs = as + 4096;
    if (kt + 1 < 16) {
      u16* an = sm + ((kt + 1) & 1) * 12288;
      stage((kt + 1) << 6, an, an + 4096);
    }
#pragma unroll
    for (int ks = 0; ks < 2; ++ks) {
      const int cfs = (ks * 32 + quad * 8) ^ rsw;
      s16x8 af[2], bf[4];
#pragma unroll
      for (int mi = 0; mi < 2; ++mi)
        af[mi] = *(const s16x8*)&as[(wm + mi * 16 + row16) * 64 + cfs];
#pragma unroll
      for (int ni = 0; ni < 4; ++ni)
        bf[ni] = *(const s16x8*)&bs[(wn + ni * 16 + row16) * 64 + cfs];
#pragma unroll
      for (int mi = 0; mi < 2; ++mi)
#pragma unroll
        for (int ni = 0; ni < 4; ++ni)
          acc[mi][ni] = __builtin_amdgcn_mfma_f32_16x16x32_bf16(af[mi], bf[ni], acc[mi][ni], 0, 0, 0);
    }
    asm volatile("s_waitcnt vmcnt(0) lgkmcnt(0)" ::: "memory");
    __builtin_amdgcn_s_barrier();
    __builtin_amdgcn_sched_barrier(0);
  }

#pragma unroll
  for (int mi = 0; mi < 2; ++mi)
#pragma unroll
    for (int ni = 0; ni < 4; ++ni) {
      const int n = n0 + wn + ni * 16 + row16;
      const float bn = bo[n];
#pragma unroll
      for (int r = 0; r < 4; ++r) {
        const int m = m0 + wm + mi * 16 + quad * 4 + r;
        out[(size_t)m * N + n] = acc[mi][ni][r] + bn;
      }
    }
}

// ---------------- fused attention (round-9-proven: T14 async-STAGE + setprio) ----
// VGPR 80, LDS 34816 -> 4 blocks/CU. Round-5 lesson: do NOT add per-iteration
// register state (2-q-tile merge -> 156 VGPR, occupancy halved, 61->82 us).
__global__ __launch_bounds__(256) void attn_fused(
    const u16* __restrict__ Q, const u16* __restrict__ Kb, const u16* __restrict__ Vt,
    const u16* __restrict__ RKp, const float* __restrict__ RV, u16* __restrict__ Y) {
  __shared__ __align__(16) float qr_sm[4][576];     // [bucket][q] stride 17
  __shared__ __align__(16) float s_sm[4][16 * 36];  // [q][bucket] stride 36
  __shared__ __align__(16) unsigned char kv[16384]; // K 8K | V 8K; rv_sm epilogue

  const int tid = threadIdx.x;
  const int wave = tid >> 6, lane = tid & 63;
  const int row16 = lane & 15, quad = lane >> 4;
  const int bh = blockIdx.x & 63;          // XCD swizzle
  const int i0 = (blockIdx.x >> 6) * 64;
  const int wq0 = i0 + wave * 16;
  const u16* qp = Q + (size_t)bh * LL * HD;
  const char* kpB = (const char*)(Kb + (size_t)bh * LL * HD);
  const char* vpB = (const char*)(Vt + (size_t)bh * HD * LL);

  float* qr_w = &qr_sm[wave][0];
  float* s_w = &s_sm[wave][0];

  // stage offsets (both-sides swizzle: linear LDS dest, pre-swizzled source)
  int srcK[2], srcV[2];
#pragma unroll
  for (int t = 0; t < 2; ++t) {
    const int cK = (wave * 2 + t) * 64 + lane;
    const int rw = cK >> 3;
    const int cb = ((cK * 16) & 127) ^ ((rw & 7) << 4);
    srcK[t] = rw * 128 + cb;
    srcV[t] = rw * 2048 + cb;
  }
  // rho' row permutation (swap 4-7 <-> 8-11 within each 16) for K reads
  const int q2 = row16 >> 2;
  const int prow = ((((q2 << 1) | (q2 >> 1)) & 3) << 2) + (row16 & 3);
  const int swzK = (prow & 7) << 4;
  const int swzV = (row16 & 7) << 4;
  const int rho4 = (((quad << 1) | (quad >> 1)) & 3) << 2;  // rho(quad)*4

  // ---- prologue: DMA tile 0, overlap with qr compute ----
#pragma unroll
  for (int t = 0; t < 2; ++t) {
    gld_lds16(kpB + srcK[t], kv + (wave * 2 + t) * 1024);
    gld_lds16(vpB + srcV[t], kv + 8192 + (wave * 2 + t) * 1024);
  }

  for (int t = lane; t < 16 * 36; t += 64) s_w[t] = 0.f;

  // Q fragments (B-operand; identical lane layout to A for 16x16x32)
  s16x8 qf[2];
#pragma unroll
  for (int ks = 0; ks < 2; ++ks)
    qf[ks] = *(const s16x8*)(qp + (size_t)(wq0 + row16) * HD + ks * 32 + quad * 8);

  // qr^T[bucket][q] = rel_k[bucket] . q  via swapped MFMA (A=RK, B=Q)
  f32x4 a0, a2;
#pragma unroll
  for (int nt = 0; nt < 3; ++nt) {
    f32x4 a = {};
#pragma unroll
    for (int ks = 0; ks < 2; ++ks) {
      s16x8 afr = *(const s16x8*)(RKp + (size_t)(nt * 16 + row16) * HD + ks * 32 + quad * 8);
      a = __builtin_amdgcn_mfma_f32_16x16x32_bf16(afr, qf[ks], a, 0, 0, 0);
    }
    if (nt == 0) a0 = a;
    if (nt == 2) a2 = a;
#pragma unroll
    for (int r = 0; r < 4; ++r) {
      const int bk = nt * 16 + quad * 4 + r;
      if (bk < NBUCKET) qr_w[bk * 17 + row16] = a[r];
    }
  }
  // far biases: bucket 0 / 32 value for this lane's q-row (= row16)
  const float blo = __shfl(a0[0], row16);
  const float bhi = __shfl(a2[0], row16);

  f32x4 oacc[4] = {};
  float rsum = 0.f, plos = 0.f, phis = 0.f;
  int baseg[4];
#pragma unroll
  for (int g = 0; g < 4; ++g) baseg[g] = g * 16 + rho4 - wq0 - row16;

  // prologue drain: tile-0 DMA + qf/qr loads complete, LDS writes visible
  asm volatile("s_waitcnt vmcnt(0) lgkmcnt(0)" ::: "memory");
  __builtin_amdgcn_s_barrier();
  __builtin_amdgcn_sched_barrier(0);

  for (int jt = 0; jt < 16; ++jt) {
    const int j0 = jt * 64;

    // ---- T14 issue: tile jt+1 K/V -> registers (vmcnt waited at ds_write) ----
    s16x8 kreg[2], vreg[2];
    if (jt < 15) {
      const size_t j1 = (size_t)(j0 + 64);
#pragma unroll
      for (int t = 0; t < 2; ++t) {
        kreg[t] = *(const s16x8*)(kpB + j1 * 128 + srcK[t]);
        vreg[t] = *(const s16x8*)(vpB + j1 * 2 + srcV[t]);
      }
    }

    // ---- S^T = K Q^T : lane holds S^T[j = j0+g*16+rho4+r][q = wq0+row16] ----
    f32x4 sacc[4] = {};
    __builtin_amdgcn_s_setprio(1);
#pragma unroll
    for (int ks = 0; ks < 2; ++ks)
#pragma unroll
      for (int g = 0; g < 4; ++g) {
        const int L = (g * 16 + prow) * 128 + ks * 64 + quad * 16;
        const s16x8 kfr = *(const s16x8*)(kv + (L ^ swzK));
        sacc[g] = __builtin_amdgcn_mfma_f32_16x16x32_bf16(kfr, qf[ks], sacc[g], 0, 0, 0);
      }
    __builtin_amdgcn_s_setprio(0);

    // ---- softmax + bf16 pack (all in registers) ----
    unsigned pk[4][2];
    const bool far_lo = (wq0 >= j0 + 79);
    const bool far_hi = (j0 >= wq0 + 31);
    if (far_lo || far_hi) {
      const float bb = (far_lo ? blo : bhi) * SC2;
      float tacc = 0.f;
#pragma unroll
      for (int g = 0; g < 4; ++g)
#pragma unroll
        for (int rr = 0; rr < 2; ++rr) {
          const float pv0 = __builtin_amdgcn_exp2f(sacc[g][rr * 2] * SC2 + bb);
          const float pv1 = __builtin_amdgcn_exp2f(sacc[g][rr * 2 + 1] * SC2 + bb);
          tacc += pv0 + pv1;
          unsigned c;
          asm("v_cvt_pk_bf16_f32 %0, %1, %2" : "=v"(c) : "v"(pv0), "v"(pv1));
          pk[g][rr] = c;
        }
      rsum += tacc;
      if (far_lo) plos += tacc; else phis += tacc;
    } else {
#pragma unroll
      for (int g = 0; g < 4; ++g)
#pragma unroll
        for (int rr = 0; rr < 2; ++rr) {
          float pv2[2];
#pragma unroll
          for (int e = 0; e < 2; ++e) {
            const int r = rr * 2 + e;
            const int dr = baseg[g] + j0 + r;
            int bk = dr < -16 ? -16 : (dr > 16 ? 16 : dr);
            bk += 16;
            const float bias = qr_w[bk * 17 + row16];
            const float pv = __builtin_amdgcn_exp2f((sacc[g][r] + bias) * SC2);
            pv2[e] = pv;
            rsum += pv;
            if (dr <= -16) plos += pv;
            else if (dr >= 16) phis += pv;
            else atomicAdd(&s_w[row16 * 36 + bk], pv);
          }
          unsigned c;
          asm("v_cvt_pk_bf16_f32 %0, %1, %2" : "=v"(c) : "v"(pv2[0]), "v"(pv2[1]));
          pk[g][rr] = c;
        }
    }

    // ---- P^T B-frag assembly: 4 permlane32_swap, zero LDS ----
    s16x8 pf[2];
#pragma unroll
    for (int ks = 0; ks < 2; ++ks) {
      unsigned x0 = pk[ks * 2][0], y0 = pk[ks * 2 + 1][0];
      unsigned x1 = pk[ks * 2][1], y1 = pk[ks * 2 + 1][1];
      asm("v_permlane32_swap_b32 %0, %1" : "+v"(x0), "+v"(y0));
      asm("v_permlane32_swap_b32 %0, %1" : "+v"(x1), "+v"(y1));
      union { unsigned u[4]; s16x8 v; } pfu;
      pfu.u[0] = x0; pfu.u[1] = x1; pfu.u[2] = y0; pfu.u[3] = y1;
      pf[ks] = pfu.v;
    }

    // ---- O^T += V^T P^T ----
    __builtin_amdgcn_s_setprio(1);
#pragma unroll
    for (int ks = 0; ks < 2; ++ks)
#pragma unroll
      for (int dt = 0; dt < 4; ++dt) {
        const int L = (dt * 16 + row16) * 128 + ks * 64 + quad * 16;
        const s16x8 vfr = *(const s16x8*)(kv + 8192 + (L ^ swzV));
        oacc[dt] = __builtin_amdgcn_mfma_f32_16x16x32_bf16(vfr, pf[ks], oacc[dt], 0, 0, 0);
      }
    __builtin_amdgcn_s_setprio(0);

    // barrier 1: all waves done READING kv for this tile
    asm volatile("s_waitcnt lgkmcnt(0)" ::: "memory");
    __builtin_amdgcn_s_barrier();
    __builtin_amdgcn_sched_barrier(0);

    // ---- T14 write: regs -> LDS (compiler waits vmcnt here, a full phase
    // after issue), then barrier 2 makes writes visible ----
    if (jt < 15) {
#pragma unroll
      for (int t = 0; t < 2; ++t) {
        *(s16x8*)(kv + (wave * 2 + t) * 1024 + lane * 16) = kreg[t];
        *(s16x8*)(kv + 8192 + (wave * 2 + t) * 1024 + lane * 16) = vreg[t];
      }
      asm volatile("s_waitcnt lgkmcnt(0)" ::: "memory");
      __builtin_amdgcn_s_barrier();
      __builtin_amdgcn_sched_barrier(0);
    }
  }

  // quad-reduction of row sums (j space was split across quads)
  float t1 = rsum + __shfl_xor(rsum, 16);
  const float lacc = t1 + __shfl_xor(t1, 32);
  t1 = plos + __shfl_xor(plos, 16);
  const float slo = t1 + __shfl_xor(t1, 32);
  t1 = phis + __shfl_xor(phis, 16);
  const float shi = t1 + __shfl_xor(t1, 32);

  // epilogue: rel_v into kv (loop-final barrier fenced all reads)
  float* rv_sm = (float*)kv;
  for (int t = tid; t < NBUCKET * HD; t += 256) rv_sm[t] = RV[t];
  __syncthreads();

  const int b = bh >> 4, h = bh & 15;
  float rel[4][4] = {};
  for (int bk = 0; bk < NBUCKET; ++bk) {
    float sv = s_w[row16 * 36 + bk];
    if (bk == 0) sv += slo;
    if (bk == 32) sv += shi;
#pragma unroll
    for (int dt = 0; dt < 4; ++dt) {
      const f32x4 rv4 = *(const f32x4*)&rv_sm[bk * HD + dt * 16 + quad * 4];
#pragma unroll
      for (int r = 0; r < 4; ++r) rel[dt][r] += sv * rv4[r];
    }
  }
  const float inv = 1.0f / lacc;
#pragma unroll
  for (int dt = 0; dt < 4; ++dt) {
    ushort4 o;
    o.x = f2bf((oacc[dt][0] + rel[dt][0]) * inv);
    o.y = f2bf((oacc[dt][1] + rel[dt][1]) * inv);
    o.z = f2bf((oacc[dt][2] + rel[dt][2]) * inv);
    o.w = f2bf((oacc[dt][3] + rel[dt][3]) * inv);
    *(ushort4*)&Y[((size_t)(b * LL + wq0 + row16)) * EE + h * HD + dt * 16 + quad * 4] = o;
  }
}

extern "C" void kernel_launch(void* const* d_in, const int* in_sizes, int n_in,
                              void* d_out, int out_size, void* d_ws, size_t ws_size,
                              hipStream_t stream) {
  const float* query = (const float*)d_in[0];
  const float* key_  = (const float*)d_in[1];
  const float* value = (const float*)d_in[2];
  const float* wq = (const float*)d_in[3];
  const float* bq = (const float*)d_in[4];
  const float* wk = (const float*)d_in[5];
  const float* bk = (const float*)d_in[6];
  const float* wv = (const float*)d_in[7];
  const float* bv = (const float*)d_in[8];
  const float* wo = (const float*)d_in[9];
  const float* bo = (const float*)d_in[10];
  const float* rel_k = (const float*)d_in[11];
  const float* rel_v = (const float*)d_in[12];

  char* base = (char*)d_ws;
  size_t off = 0;
  auto alloc = [&](size_t bytes) -> void* {
    void* p = base + off;
    off += (bytes + 255) & ~(size_t)255;
    return p;
  };
  const size_t XE = (size_t)BB * LL * EE;
  u16* wqb   = (u16*)alloc((size_t)EE * EE * 2);
  u16* wkb   = (u16*)alloc((size_t)EE * EE * 2);
  u16* wvb   = (u16*)alloc((size_t)EE * EE * 2);
  u16* wob   = (u16*)alloc((size_t)EE * EE * 2);
  u16* q_ws  = (u16*)alloc(XE * 2);
  u16* k_ws  = (u16*)alloc(XE * 2);
  u16* vt_ws = (u16*)alloc(XE * 2);   // V stored transposed by proj_gemm
  u16* relkp = (u16*)alloc(48 * 64 * 2);
  u16* y_ws  = (u16*)alloc(XE * 2);

  cvt_w<<<4108, 256, 0, stream>>>(wq, wk, wv, wo, rel_k, wqb, wkb, wvb, wob, relkp);

  proj_gemm<<<768, 256, 0, stream>>>(
      query, key_, value, wqb, wkb, wvb, bq, bk, bv, q_ws, k_ws, vt_ws);

  attn_fused<<<1024, 256, 0, stream>>>(q_ws, k_ws, vt_ws, relkp, rel_v, y_ws);

  out_gemm<<<512, 256, 0, stream>>>(y_ws, wob, bo, (float*)d_out);
}

// Round 13
// 224.934 us; speedup vs baseline: 1.0584x; 1.0584x over previous
//
#include <hip/hip_runtime.h>

#define BB 4
#define LL 1024
#define EE 1024
#define HH 16
#define HD 64
#define NBUCKET 33
#define SCALE 0.125f
#define SC2 (0.125f * 1.44269504088896f)

typedef unsigned short u16;
using f32x4 = __attribute__((ext_vector_type(4))) float;
using s16x8 = __attribute__((ext_vector_type(8))) short;

__device__ __forceinline__ u16 f2bf(float f) {
  union { float f; unsigned u; } x; x.f = f;
  unsigned r = (x.u + 0x7fffu + ((x.u >> 16) & 1u)) >> 16;
  return (u16)r;
}

__device__ __forceinline__ void gld_lds16(const void* g, void* s) {
  __builtin_amdgcn_global_load_lds((const __attribute__((address_space(1))) void*)g,
                                   (__attribute__((address_space(3))) void*)s, 16, 0, 0);
}

// ---------------- fp32 -> bf16 converts (single merged launch) ----------------
// [0,12288) q/k/v inputs, [12288,16384) weights, [16384,16396) rel_k pad 48x64.
// NOTE round-12 evidence: fusing the input convert into proj (T14 reg-staged
// f32 A) REGRESSED proj 55->68 us — the cvt+ds_write landed on the critical
// path each K-step, and the A panels were L2-resident anyway. Keep the
// streaming pre-pass.
__global__ __launch_bounds__(256) void cvt_all(
    const float* __restrict__ q, const float* __restrict__ k, const float* __restrict__ v,
    const float* __restrict__ wq, const float* __restrict__ wk, const float* __restrict__ wv,
    const float* __restrict__ wo, const float* __restrict__ rk,
    u16* __restrict__ oq, u16* __restrict__ ok, u16* __restrict__ ov,
    u16* __restrict__ owq, u16* __restrict__ owk, u16* __restrict__ owv,
    u16* __restrict__ owo, u16* __restrict__ ork) {
  const int bid = blockIdx.x;
  const int tid = threadIdx.x;
  if (bid < 12288) {
    const int z = bid >> 12;
    const int i = (bid & 4095) * 256 + tid;
    const float* in = z == 0 ? q : (z == 1 ? k : v);
    u16* out = z == 0 ? oq : (z == 1 ? ok : ov);
    float4 f = ((const float4*)in)[i];
    ushort4 o;
    o.x = f2bf(f.x); o.y = f2bf(f.y); o.z = f2bf(f.z); o.w = f2bf(f.w);
    ((ushort4*)out)[i] = o;
  } else if (bid < 16384) {
    const int z = (bid - 12288) >> 10;
    const int i = ((bid - 12288) & 1023) * 256 + tid;
    const float* in = z == 0 ? wq : (z == 1 ? wk : (z == 2 ? wv : wo));
    u16* out = z == 0 ? owq : (z == 1 ? owk : (z == 2 ? owv : owo));
    float4 f = ((const float4*)in)[i];
    ushort4 o;
    o.x = f2bf(f.x); o.y = f2bf(f.y); o.z = f2bf(f.z); o.w = f2bf(f.w);
    ((ushort4*)out)[i] = o;
  } else {
    const int i = (bid - 16384) * 256 + tid;  // 12*256 = 3072 = 48*64 exact
    ork[i] = (i < 33 * 64) ? f2bf(rk[i]) : (u16)0;
  }
}

// ------- 128x128x64 double-buffered all-DMA bf16 GEMM, C = A * B^T + bias ------
// Round-8-proven: stage(kt+1) at iter TOP into alt buffer; ONE drain+barrier
// at iter END. Both-sides swizzle. XCD-chunk remap in callers.
// MODE 0: bf16 (B,H,L,HD). MODE 2: bf16 (B,H,HD,L).
template <int MODE>
__device__ __forceinline__ void gemm128_dbuf(u16* __restrict__ sm,  // 4 x 8192 u16
                                             const u16* __restrict__ A,
                                             const u16* __restrict__ Bw,
                                             const float* __restrict__ bias,
                                             u16* __restrict__ obf,
                                             float* __restrict__ ofp,
                                             int N, int K, int m0, int n0) {
  const int tid = threadIdx.x;
  const int wave = tid >> 6, lane = tid & 63;
  const int row16 = lane & 15, quad = lane >> 4;
  const int wr = (wave >> 1) * 64, wc = (wave & 1) * 64;
  const int srow = lane >> 3, scol = (lane & 7) * 8;
  const int rsw = (row16 & 7) * 8;  // frag-read XOR (u16 units)

  f32x4 acc[4][4] = {};

  auto stage = [&](int k0, u16* as, u16* bs) {
#pragma unroll
    for (int t = 0; t < 4; ++t) {
      const int chunk = wave * 4 + t;
      const int r = chunk * 8 + srow;
      const int cs = scol ^ ((r & 7) * 8);
      gld_lds16(A + (size_t)(m0 + r) * K + k0 + cs, as + chunk * 512);
      gld_lds16(Bw + (size_t)(n0 + r) * K + k0 + cs, bs + chunk * 512);
    }
  };

  // prologue: stage tile 0, drain, barrier
  stage(0, sm, sm + 8192);
  asm volatile("s_waitcnt vmcnt(0)" ::: "memory");
  __builtin_amdgcn_s_barrier();
  __builtin_amdgcn_sched_barrier(0);

  const int NK = K >> 6;
  for (int kt = 0; kt < NK; ++kt) {
    u16* as = sm + (kt & 1) * 16384;
    u16* bs = as + 8192;
    if (kt + 1 < NK) {
      u16* an = sm + ((kt + 1) & 1) * 16384;
      stage((kt + 1) << 6, an, an + 8192);
    }
#pragma unroll
    for (int ks = 0; ks < 2; ++ks) {
      const int cfs = (ks * 32 + quad * 8) ^ rsw;
      s16x8 af[4], bf[4];
#pragma unroll
      for (int mi = 0; mi < 4; ++mi)
        af[mi] = *(const s16x8*)&as[(wr + mi * 16 + row16) * 64 + cfs];
#pragma unroll
      for (int ni = 0; ni < 4; ++ni)
        bf[ni] = *(const s16x8*)&bs[(wc + ni * 16 + row16) * 64 + cfs];
#pragma unroll
      for (int mi = 0; mi < 4; ++mi)
#pragma unroll
        for (int ni = 0; ni < 4; ++ni)
          acc[mi][ni] = __builtin_amdgcn_mfma_f32_16x16x32_bf16(af[mi], bf[ni], acc[mi][ni], 0, 0, 0);
    }
    // single end-of-iter drain: my ds_reads retired (lgkm) + next tile's DMA
    // (issued at iter top, covered by this compute phase) landed (vmcnt).
    asm volatile("s_waitcnt vmcnt(0) lgkmcnt(0)" ::: "memory");
    __builtin_amdgcn_s_barrier();
    __builtin_amdgcn_sched_barrier(0);
  }

#pragma unroll
  for (int mi = 0; mi < 4; ++mi)
#pragma unroll
    for (int ni = 0; ni < 4; ++ni) {
      const int n = n0 + wc + ni * 16 + row16;
      const float bn = bias[n];
      if (MODE == 2) {
        const int mr0 = m0 + wr + mi * 16 + quad * 4;
        const int b = mr0 >> 10, l = mr0 & 1023;
        const int h = n >> 6, hd = n & 63;
        ushort4 o;
        o.x = f2bf(acc[mi][ni][0] + bn);
        o.y = f2bf(acc[mi][ni][1] + bn);
        o.z = f2bf(acc[mi][ni][2] + bn);
        o.w = f2bf(acc[mi][ni][3] + bn);
        *(ushort4*)&obf[((size_t)((b * HH + h) * HD + hd)) * LL + l] = o;
      } else {
#pragma unroll
        for (int r = 0; r < 4; ++r) {
          const int m = m0 + wr + mi * 16 + quad * 4 + r;
          const float v = acc[mi][ni][r] + bn;
          const int b = m >> 10, l = m & 1023, h = n >> 6, hd = n & 63;
          obf[((size_t)((b * HH + h) * LL + l)) * HD + hd] = f2bf(v);
        }
      }
    }
}

__global__ __launch_bounds__(256) void proj_gemm(
    const u16* __restrict__ xq, const u16* __restrict__ xk, const u16* __restrict__ xv,
    const u16* __restrict__ wqb, const u16* __restrict__ wkb, const u16* __restrict__ wvb,
    const float* __restrict__ bq, const float* __restrict__ bk, const float* __restrict__ bv,
    u16* __restrict__ oq, u16* __restrict__ ok, u16* __restrict__ ovt) {
  __shared__ u16 sm[4 * 8192];  // dbuf: {a0,b0,a1,b1}
  const int work = (blockIdx.x & 7) * 96 + (blockIdx.x >> 3);
  const int z = work >> 8;
  const int m0 = ((work & 255) >> 3) * 128;
  const int n0 = (work & 7) * 128;
  if (z == 0)
    gemm128_dbuf<0>(sm, xq, wqb, bq, oq, nullptr, EE, EE, m0, n0);
  else if (z == 1)
    gemm128_dbuf<0>(sm, xk, wkb, bk, ok, nullptr, EE, EE, m0, n0);
  else  // V: store directly transposed (B,H,HD,L)
    gemm128_dbuf<2>(sm, xv, wvb, bv, ovt, nullptr, EE, EE, m0, n0);
}

// ---------------- out projection: 64x128x64 dbuf GEMM (round-10-proven) --------
__global__ __launch_bounds__(256) void out_gemm(const u16* __restrict__ A,
                                                const u16* __restrict__ Bw,
                                                const float* __restrict__ bo,
                                                float* __restrict__ out) {
  __shared__ u16 sm[2 * 12288];  // per buf: A 4096 u16 (64x64) | B 8192 u16 (128x64)
  const int work = (blockIdx.x & 7) * 64 + (blockIdx.x >> 3);
  const int m0 = (work >> 3) * 64;
  const int n0 = (work & 7) * 128;
  const int K = EE, N = EE;

  const int tid = threadIdx.x;
  const int wave = tid >> 6, lane = tid & 63;
  const int row16 = lane & 15, quad = lane >> 4;
  const int wm = (wave >> 1) * 32, wn = (wave & 1) * 64;
  const int srow = lane >> 3, scol = (lane & 7) * 8;
  const int rsw = (row16 & 7) * 8;

  f32x4 acc[2][4] = {};

  auto stage = [&](int k0, u16* as, u16* bs) {
#pragma unroll
    for (int t = 0; t < 2; ++t) {
      const int chunk = wave * 2 + t;
      const int r = chunk * 8 + srow;
      const int cs = scol ^ ((r & 7) * 8);
      gld_lds16(A + (size_t)(m0 + r) * K + k0 + cs, as + chunk * 512);
    }
#pragma unroll
    for (int t = 0; t < 4; ++t) {
      const int chunk = wave * 4 + t;
      const int r = chunk * 8 + srow;
      const int cs = scol ^ ((r & 7) * 8);
      gld_lds16(Bw + (size_t)(n0 + r) * K + k0 + cs, bs + chunk * 512);
    }
  };

  stage(0, sm, sm + 4096);
  asm volatile("s_waitcnt vmcnt(0)" ::: "memory");
  __builtin_amdgcn_s_barrier();
  __builtin_amdgcn_sched_barrier(0);

  for (int kt = 0; kt < 16; ++kt) {
    u16* as = sm + (kt & 1) * 12288;
    u16* bs = as + 4096;
    if (kt + 1 < 16) {
      u16* an = sm + ((kt + 1) & 1) * 12288;
      stage((kt + 1) << 6, an, an + 4096);
    }
#pragma unroll
    for (int ks = 0; ks < 2; ++ks) {
      const int cfs = (ks * 32 + quad * 8) ^ rsw;
      s16x8 af[2], bf[4];
#pragma unroll
      for (int mi = 0; mi < 2; ++mi)
        af[mi] = *(const s16x8*)&as[(wm + mi * 16 + row16) * 64 + cfs];
#pragma unroll
      for (int ni = 0; ni < 4; ++ni)
        bf[ni] = *(const s16x8*)&bs[(wn + ni * 16 + row16) * 64 + cfs];
#pragma unroll
      for (int mi = 0; mi < 2; ++mi)
#pragma unroll
        for (int ni = 0; ni < 4; ++ni)
          acc[mi][ni] = __builtin_amdgcn_mfma_f32_16x16x32_bf16(af[mi], bf[ni], acc[mi][ni], 0, 0, 0);
    }
    asm volatile("s_waitcnt vmcnt(0) lgkmcnt(0)" ::: "memory");
    __builtin_amdgcn_s_barrier();
    __builtin_amdgcn_sched_barrier(0);
  }

#pragma unroll
  for (int mi = 0; mi < 2; ++mi)
#pragma unroll
    for (int ni = 0; ni < 4; ++ni) {
      const int n = n0 + wn + ni * 16 + row16;
      const float bn = bo[n];
#pragma unroll
      for (int r = 0; r < 4; ++r) {
        const int m = m0 + wm + mi * 16 + quad * 4 + r;
        out[(size_t)m * N + n] = acc[mi][ni][r] + bn;
      }
    }
}

// ---------------- fused attention (round-9-proven: T14 async-STAGE + setprio) ----
// VGPR 80, LDS 34816 -> 4 blocks/CU. Round-5 lesson: do NOT add per-iteration
// register state (2-q-tile merge -> 156 VGPR, occupancy halved, 61->82 us).
__global__ __launch_bounds__(256) void attn_fused(
    const u16* __restrict__ Q, const u16* __restrict__ Kb, const u16* __restrict__ Vt,
    const u16* __restrict__ RKp, const float* __restrict__ RV, u16* __restrict__ Y) {
  __shared__ __align__(16) float qr_sm[4][576];     // [bucket][q] stride 17
  __shared__ __align__(16) float s_sm[4][16 * 36];  // [q][bucket] stride 36
  __shared__ __align__(16) unsigned char kv[16384]; // K 8K | V 8K; rv_sm epilogue

  const int tid = threadIdx.x;
  const int wave = tid >> 6, lane = tid & 63;
  const int row16 = lane & 15, quad = lane >> 4;
  const int bh = blockIdx.x & 63;          // XCD swizzle
  const int i0 = (blockIdx.x >> 6) * 64;
  const int wq0 = i0 + wave * 16;
  const u16* qp = Q + (size_t)bh * LL * HD;
  const char* kpB = (const char*)(Kb + (size_t)bh * LL * HD);
  const char* vpB = (const char*)(Vt + (size_t)bh * HD * LL);

  float* qr_w = &qr_sm[wave][0];
  float* s_w = &s_sm[wave][0];

  // stage offsets (both-sides swizzle: linear LDS dest, pre-swizzled source)
  int srcK[2], srcV[2];
#pragma unroll
  for (int t = 0; t < 2; ++t) {
    const int cK = (wave * 2 + t) * 64 + lane;
    const int rw = cK >> 3;
    const int cb = ((cK * 16) & 127) ^ ((rw & 7) << 4);
    srcK[t] = rw * 128 + cb;
    srcV[t] = rw * 2048 + cb;
  }
  // rho' row permutation (swap 4-7 <-> 8-11 within each 16) for K reads
  const int q2 = row16 >> 2;
  const int prow = ((((q2 << 1) | (q2 >> 1)) & 3) << 2) + (row16 & 3);
  const int swzK = (prow & 7) << 4;
  const int swzV = (row16 & 7) << 4;
  const int rho4 = (((quad << 1) | (quad >> 1)) & 3) << 2;  // rho(quad)*4

  // ---- prologue: DMA tile 0, overlap with qr compute ----
#pragma unroll
  for (int t = 0; t < 2; ++t) {
    gld_lds16(kpB + srcK[t], kv + (wave * 2 + t) * 1024);
    gld_lds16(vpB + srcV[t], kv + 8192 + (wave * 2 + t) * 1024);
  }

  for (int t = lane; t < 16 * 36; t += 64) s_w[t] = 0.f;

  // Q fragments (B-operand; identical lane layout to A for 16x16x32)
  s16x8 qf[2];
#pragma unroll
  for (int ks = 0; ks < 2; ++ks)
    qf[ks] = *(const s16x8*)(qp + (size_t)(wq0 + row16) * HD + ks * 32 + quad * 8);

  // qr^T[bucket][q] = rel_k[bucket] . q  via swapped MFMA (A=RK, B=Q)
  f32x4 a0, a2;
#pragma unroll
  for (int nt = 0; nt < 3; ++nt) {
    f32x4 a = {};
#pragma unroll
    for (int ks = 0; ks < 2; ++ks) {
      s16x8 afr = *(const s16x8*)(RKp + (size_t)(nt * 16 + row16) * HD + ks * 32 + quad * 8);
      a = __builtin_amdgcn_mfma_f32_16x16x32_bf16(afr, qf[ks], a, 0, 0, 0);
    }
    if (nt == 0) a0 = a;
    if (nt == 2) a2 = a;
#pragma unroll
    for (int r = 0; r < 4; ++r) {
      const int bk = nt * 16 + quad * 4 + r;
      if (bk < NBUCKET) qr_w[bk * 17 + row16] = a[r];
    }
  }
  // far biases: bucket 0 / 32 value for this lane's q-row (= row16)
  const float blo = __shfl(a0[0], row16);
  const float bhi = __shfl(a2[0], row16);

  f32x4 oacc[4] = {};
  float rsum = 0.f, plos = 0.f, phis = 0.f;
  int baseg[4];
#pragma unroll
  for (int g = 0; g < 4; ++g) baseg[g] = g * 16 + rho4 - wq0 - row16;

  // prologue drain: tile-0 DMA + qf/qr loads complete, LDS writes visible
  asm volatile("s_waitcnt vmcnt(0) lgkmcnt(0)" ::: "memory");
  __builtin_amdgcn_s_barrier();
  __builtin_amdgcn_sched_barrier(0);

  for (int jt = 0; jt < 16; ++jt) {
    const int j0 = jt * 64;

    // ---- T14 issue: tile jt+1 K/V -> registers (vmcnt waited at ds_write) ----
    s16x8 kreg[2], vreg[2];
    if (jt < 15) {
      const size_t j1 = (size_t)(j0 + 64);
#pragma unroll
      for (int t = 0; t < 2; ++t) {
        kreg[t] = *(const s16x8*)(kpB + j1 * 128 + srcK[t]);
        vreg[t] = *(const s16x8*)(vpB + j1 * 2 + srcV[t]);
      }
    }

    // ---- S^T = K Q^T : lane holds S^T[j = j0+g*16+rho4+r][q = wq0+row16] ----
    f32x4 sacc[4] = {};
    __builtin_amdgcn_s_setprio(1);
#pragma unroll
    for (int ks = 0; ks < 2; ++ks)
#pragma unroll
      for (int g = 0; g < 4; ++g) {
        const int L = (g * 16 + prow) * 128 + ks * 64 + quad * 16;
        const s16x8 kfr = *(const s16x8*)(kv + (L ^ swzK));
        sacc[g] = __builtin_amdgcn_mfma_f32_16x16x32_bf16(kfr, qf[ks], sacc[g], 0, 0, 0);
      }
    __builtin_amdgcn_s_setprio(0);

    // ---- softmax + bf16 pack (all in registers) ----
    unsigned pk[4][2];
    const bool far_lo = (wq0 >= j0 + 79);
    const bool far_hi = (j0 >= wq0 + 31);
    if (far_lo || far_hi) {
      const float bb = (far_lo ? blo : bhi) * SC2;
      float tacc = 0.f;
#pragma unroll
      for (int g = 0; g < 4; ++g)
#pragma unroll
        for (int rr = 0; rr < 2; ++rr) {
          const float pv0 = __builtin_amdgcn_exp2f(sacc[g][rr * 2] * SC2 + bb);
          const float pv1 = __builtin_amdgcn_exp2f(sacc[g][rr * 2 + 1] * SC2 + bb);
          tacc += pv0 + pv1;
          unsigned c;
          asm("v_cvt_pk_bf16_f32 %0, %1, %2" : "=v"(c) : "v"(pv0), "v"(pv1));
          pk[g][rr] = c;
        }
      rsum += tacc;
      if (far_lo) plos += tacc; else phis += tacc;
    } else {
#pragma unroll
      for (int g = 0; g < 4; ++g)
#pragma unroll
        for (int rr = 0; rr < 2; ++rr) {
          float pv2[2];
#pragma unroll
          for (int e = 0; e < 2; ++e) {
            const int r = rr * 2 + e;
            const int dr = baseg[g] + j0 + r;
            int bk = dr < -16 ? -16 : (dr > 16 ? 16 : dr);
            bk += 16;
            const float bias = qr_w[bk * 17 + row16];
            const float pv = __builtin_amdgcn_exp2f((sacc[g][r] + bias) * SC2);
            pv2[e] = pv;
            rsum += pv;
            if (dr <= -16) plos += pv;
            else if (dr >= 16) phis += pv;
            else atomicAdd(&s_w[row16 * 36 + bk], pv);
          }
          unsigned c;
          asm("v_cvt_pk_bf16_f32 %0, %1, %2" : "=v"(c) : "v"(pv2[0]), "v"(pv2[1]));
          pk[g][rr] = c;
        }
    }

    // ---- P^T B-frag assembly: 4 permlane32_swap, zero LDS ----
    s16x8 pf[2];
#pragma unroll
    for (int ks = 0; ks < 2; ++ks) {
      unsigned x0 = pk[ks * 2][0], y0 = pk[ks * 2 + 1][0];
      unsigned x1 = pk[ks * 2][1], y1 = pk[ks * 2 + 1][1];
      asm("v_permlane32_swap_b32 %0, %1" : "+v"(x0), "+v"(y0));
      asm("v_permlane32_swap_b32 %0, %1" : "+v"(x1), "+v"(y1));
      union { unsigned u[4]; s16x8 v; } pfu;
      pfu.u[0] = x0; pfu.u[1] = x1; pfu.u[2] = y0; pfu.u[3] = y1;
      pf[ks] = pfu.v;
    }

    // ---- O^T += V^T P^T ----
    __builtin_amdgcn_s_setprio(1);
#pragma unroll
    for (int ks = 0; ks < 2; ++ks)
#pragma unroll
      for (int dt = 0; dt < 4; ++dt) {
        const int L = (dt * 16 + row16) * 128 + ks * 64 + quad * 16;
        const s16x8 vfr = *(const s16x8*)(kv + 8192 + (L ^ swzV));
        oacc[dt] = __builtin_amdgcn_mfma_f32_16x16x32_bf16(vfr, pf[ks], oacc[dt], 0, 0, 0);
      }
    __builtin_amdgcn_s_setprio(0);

    // barrier 1: all waves done READING kv for this tile
    asm volatile("s_waitcnt lgkmcnt(0)" ::: "memory");
    __builtin_amdgcn_s_barrier();
    __builtin_amdgcn_sched_barrier(0);

    // ---- T14 write: regs -> LDS (compiler waits vmcnt here, a full phase
    // after issue), then barrier 2 makes writes visible ----
    if (jt < 15) {
#pragma unroll
      for (int t = 0; t < 2; ++t) {
        *(s16x8*)(kv + (wave * 2 + t) * 1024 + lane * 16) = kreg[t];
        *(s16x8*)(kv + 8192 + (wave * 2 + t) * 1024 + lane * 16) = vreg[t];
      }
      asm volatile("s_waitcnt lgkmcnt(0)" ::: "memory");
      __builtin_amdgcn_s_barrier();
      __builtin_amdgcn_sched_barrier(0);
    }
  }

  // quad-reduction of row sums (j space was split across quads)
  float t1 = rsum + __shfl_xor(rsum, 16);
  const float lacc = t1 + __shfl_xor(t1, 32);
  t1 = plos + __shfl_xor(plos, 16);
  const float slo = t1 + __shfl_xor(t1, 32);
  t1 = phis + __shfl_xor(phis, 16);
  const float shi = t1 + __shfl_xor(t1, 32);

  // epilogue: rel_v into kv (loop-final barrier fenced all reads)
  float* rv_sm = (float*)kv;
  for (int t = tid; t < NBUCKET * HD; t += 256) rv_sm[t] = RV[t];
  __syncthreads();

  const int b = bh >> 4, h = bh & 15;
  float rel[4][4] = {};
  for (int bk = 0; bk < NBUCKET; ++bk) {
    float sv = s_w[row16 * 36 + bk];
    if (bk == 0) sv += slo;
    if (bk == 32) sv += shi;
#pragma unroll
    for (int dt = 0; dt < 4; ++dt) {
      const f32x4 rv4 = *(const f32x4*)&rv_sm[bk * HD + dt * 16 + quad * 4];
#pragma unroll
      for (int r = 0; r < 4; ++r) rel[dt][r] += sv * rv4[r];
    }
  }
  const float inv = 1.0f / lacc;
#pragma unroll
  for (int dt = 0; dt < 4; ++dt) {
    ushort4 o;
    o.x = f2bf((oacc[dt][0] + rel[dt][0]) * inv);
    o.y = f2bf((oacc[dt][1] + rel[dt][1]) * inv);
    o.z = f2bf((oacc[dt][2] + rel[dt][2]) * inv);
    o.w = f2bf((oacc[dt][3] + rel[dt][3]) * inv);
    *(ushort4*)&Y[((size_t)(b * LL + wq0 + row16)) * EE + h * HD + dt * 16 + quad * 4] = o;
  }
}

extern "C" void kernel_launch(void* const* d_in, const int* in_sizes, int n_in,
                              void* d_out, int out_size, void* d_ws, size_t ws_size,
                              hipStream_t stream) {
  const float* query = (const float*)d_in[0];
  const float* key_  = (const float*)d_in[1];
  const float* value = (const float*)d_in[2];
  const float* wq = (const float*)d_in[3];
  const float* bq = (const float*)d_in[4];
  const float* wk = (const float*)d_in[5];
  const float* bk = (const float*)d_in[6];
  const float* wv = (const float*)d_in[7];
  const float* bv = (const float*)d_in[8];
  const float* wo = (const float*)d_in[9];
  const float* bo = (const float*)d_in[10];
  const float* rel_k = (const float*)d_in[11];
  const float* rel_v = (const float*)d_in[12];

  char* base = (char*)d_ws;
  size_t off = 0;
  auto alloc = [&](size_t bytes) -> void* {
    void* p = base + off;
    off += (bytes + 255) & ~(size_t)255;
    return p;
  };
  const size_t XE = (size_t)BB * LL * EE;
  u16* xq    = (u16*)alloc(XE * 2);
  u16* xk    = (u16*)alloc(XE * 2);
  u16* xv    = (u16*)alloc(XE * 2);
  u16* wqb   = (u16*)alloc((size_t)EE * EE * 2);
  u16* wkb   = (u16*)alloc((size_t)EE * EE * 2);
  u16* wvb   = (u16*)alloc((size_t)EE * EE * 2);
  u16* wob   = (u16*)alloc((size_t)EE * EE * 2);
  u16* q_ws  = (u16*)alloc(XE * 2);
  u16* k_ws  = (u16*)alloc(XE * 2);
  u16* vt_ws = (u16*)alloc(XE * 2);   // V stored transposed by proj_gemm
  u16* relkp = (u16*)alloc(48 * 64 * 2);
  u16* y_ws = xq;   // xq dead after proj_gemm (stream-ordered)

  cvt_all<<<16396, 256, 0, stream>>>(query, key_, value, wq, wk, wv, wo, rel_k,
                                     xq, xk, xv, wqb, wkb, wvb, wob, relkp);

  proj_gemm<<<768, 256, 0, stream>>>(
      xq, xk, xv, wqb, wkb, wvb, bq, bk, bv, q_ws, k_ws, vt_ws);

  attn_fused<<<1024, 256, 0, stream>>>(q_ws, k_ws, vt_ws, relkp, rel_v, y_ws);

  out_gemm<<<512, 256, 0, stream>>>(y_ws, wob, bo, (float*)d_out);
}